// Round 7
// baseline (476.797 us; speedup 1.0000x reference)
//
#include <hip/hip_runtime.h>

typedef __attribute__((ext_vector_type(4))) float f32x4;
typedef __attribute__((ext_vector_type(4))) int   i32x4;

static constexpr int Kd = 4096, Nd = 16384, Md = 1024;
static constexpr int BK = 128;          // K-elems (i8 bytes) per tile
static constexpr int NT = Kd / BK;      // 32 K-tiles

// ---------- helpers ----------

__device__ __forceinline__ void gload16(const char* g, char* l) {
    __builtin_amdgcn_global_load_lds(
        (const __attribute__((address_space(1))) void*)g,
        (__attribute__((address_space(3))) void*)l, 16, 0, 0);
}

__device__ __forceinline__ int pack4(int a, int b, int c, int d) {
    return (a & 255) | ((b & 255) << 8) | ((c & 255) << 16) | (d << 24);
}

// ---------- convert X: f32 [M][K] -> per-row absmax-scaled int8 ----------

__global__ __launch_bounds__(256) void convert_x_kernel(
    const float* __restrict__ x, char* __restrict__ xb, float* __restrict__ xs) {
    const int row = blockIdx.x;
    const int t   = threadIdx.x;
    const float* xr = x + (size_t)row * Kd;

    f32x4 v[4];
    float amax = 0.f;
    #pragma unroll
    for (int i = 0; i < 4; ++i) {
        v[i] = *(const f32x4*)(xr + t * 16 + i * 4);
        #pragma unroll
        for (int j = 0; j < 4; ++j) amax = fmaxf(amax, fabsf(v[i][j]));
    }
    #pragma unroll
    for (int off = 32; off; off >>= 1)
        amax = fmaxf(amax, __shfl_xor(amax, off));
    __shared__ float wmax[4];
    if ((t & 63) == 0) wmax[t >> 6] = amax;
    __syncthreads();
    amax = fmaxf(fmaxf(wmax[0], wmax[1]), fmaxf(wmax[2], wmax[3]));
    amax = fmaxf(amax, 1e-20f);

    const float inv = 127.0f / amax;
    i32x4 o;
    #pragma unroll
    for (int i = 0; i < 4; ++i) {
        int q[4];
        #pragma unroll
        for (int j = 0; j < 4; ++j) {
            int qi = __float2int_rn(v[i][j] * inv);
            qi = qi > 127 ? 127 : (qi < -127 ? -127 : qi);
            q[j] = qi;
        }
        o[i] = pack4(q[0], q[1], q[2], q[3]);
    }
    *(i32x4*)(xb + (size_t)row * Kd + t * 16) = o;
    if (t == 0) xs[row] = amax * (1.0f / 127.0f);
}

// ---------- fused 256x256 i8 GEMM: W read as raw int32, packed in-reg ----------
// C[m,n] = sw[n]*xs[m] * sum_k xq[m,k]*w8[n,k] + bias[n],  w8 = low byte of Wq
// 8 waves = 2M x 4N; per-wave 128x64 out; BK=128; A: i8 via LDS (64 KiB,
// 2 slots, XOR swizzle, gload_lds) exactly as r5/r6. B: raw int32 loaded
// one j-half ahead into a SINGLE shared raw buffer (64 VGPR), packed to i8
// frags (pack4) just-in-time. Quad order (0,1),(0,0),(1,1),(1,0) so each
// packed half's last use frees its regs before the next raw issue.
// Per-tile FIFO + waits (verified incl. prologue/tail):
//   entry: [b1raw(t):16 in flight]; A(t) in LDS
//   READ_A(af,0); vmcnt(0)+pack bfp1; issue b0raw(t) [16];
//   STAGE_A(t+1) [4]; lgkm0; Q01; vmcnt(4)+pack bfp0; Q00;
//   READ_A(af,1); lgkm0; Q11; issue b1raw(t+1); Q10; vmcnt(16); barrier.

#define BARRIER() asm volatile("s_barrier" ::: "memory")

#define LGKM0_FENCE() do {                                                     \
    asm volatile("s_waitcnt lgkmcnt(0)");                                      \
    __builtin_amdgcn_sched_barrier(0);                                         \
} while (0)

#define VMCNT(n) do {                                                          \
    asm volatile("s_waitcnt vmcnt(" #n ")" ::: "memory");                      \
    __builtin_amdgcn_sched_barrier(0);                                         \
} while (0)

#define STAGE_AFULL(slot, kt) do {                                             \
    _Pragma("unroll")                                                          \
    for (int h_ = 0; h_ < 2; ++h_) {                                           \
        char* lb_ = &LDSA[slot][h_][w * 8][0];                                 \
        gload16(Ab + (aRow0 + h_ * 64) * (size_t)Kd + (kt) * BK + gcol, lb_);  \
        gload16(Ab + (aRow0 + h_ * 64 + 128) * (size_t)Kd + (kt) * BK + gcol,  \
                lb_ + 64 * 128);                                               \
    }                                                                          \
    __builtin_amdgcn_sched_barrier(0);                                         \
} while (0)

// issue 16 dwordx4 raw int32 loads for j-half (j): frags (ni,kk), 4 loads each
#define LOAD_BRAW(j, kt) do {                                                  \
    _Pragma("unroll")                                                          \
    for (int ni = 0; ni < 2; ++ni)                                             \
        _Pragma("unroll")                                                      \
        for (int kk = 0; kk < 2; ++kk) {                                       \
            const int off_ = bOff0 + ((j) * 32 + ni * 16) * Kd                 \
                             + (kt) * BK + kk * 64;                            \
            _Pragma("unroll")                                                  \
            for (int i = 0; i < 4; ++i)                                        \
                raw[ni][kk][i] = *(const i32x4*)(bBase + off_ + i * 4);        \
        }                                                                      \
    __builtin_amdgcn_sched_barrier(0);                                         \
} while (0)

#define PACK_BF(bfp) do {                                                      \
    _Pragma("unroll")                                                          \
    for (int ni = 0; ni < 2; ++ni)                                             \
        _Pragma("unroll")                                                      \
        for (int kk = 0; kk < 2; ++kk)                                         \
            _Pragma("unroll")                                                  \
            for (int i = 0; i < 4; ++i)                                        \
                bfp[ni][kk][i] = pack4(raw[ni][kk][i][0], raw[ni][kk][i][1],   \
                                       raw[ni][kk][i][2], raw[ni][kk][i][3]);  \
} while (0)

#define READ_A(dst, slot, h) do {                                              \
    const char* lA_ = &LDSA[slot][h][0][0];                                    \
    _Pragma("unroll")                                                          \
    for (int mi = 0; mi < 4; ++mi)                                             \
        _Pragma("unroll")                                                      \
        for (int kk = 0; kk < 2; ++kk) {                                       \
            const int row_ = wm * 64 + mi * 16 + lr;                           \
            const int col_ = (l4 * 16 + kk * 64) ^ xorv;                       \
            dst[mi][kk] = *(const i32x4*)(lA_ + row_ * 128 + col_);            \
        }                                                                      \
} while (0)

#define MFMA_QUAD(h, j, AF, BF) do {                                           \
    __builtin_amdgcn_s_setprio(1);                                             \
    _Pragma("unroll")                                                          \
    for (int mi = 0; mi < 4; ++mi)                                             \
        _Pragma("unroll")                                                      \
        for (int ni = 0; ni < 2; ++ni)                                         \
            _Pragma("unroll")                                                  \
            for (int kk = 0; kk < 2; ++kk)                                     \
                acc[(h) * 4 + mi][(j) * 2 + ni] =                              \
                    __builtin_amdgcn_mfma_i32_16x16x64_i8(                     \
                        AF[mi][kk], BF[ni][kk],                                \
                        acc[(h) * 4 + mi][(j) * 2 + ni], 0, 0, 0);             \
    __builtin_amdgcn_s_setprio(0);                                             \
} while (0)

#define TILE(slot, oslot, t) do {                                              \
    READ_A(af, slot, 0);                                                       \
    VMCNT(0);                     /* b1raw(t) done */                          \
    PACK_BF(bfp1);                                                             \
    LOAD_BRAW(0, t);              /* b0raw(t) -> [b0:16] */                    \
    if ((t) + 1 < NT) STAGE_AFULL(oslot, (t) + 1);   /* -> [b0:16, A:4] */     \
    LGKM0_FENCE();                                                             \
    MFMA_QUAD(0, 1, af, bfp1);                                                 \
    if ((t) + 1 < NT) { VMCNT(4); } else { VMCNT(0); }  /* b0raw done */       \
    PACK_BF(bfp0);                                                             \
    MFMA_QUAD(0, 0, af, bfp0);                                                 \
    READ_A(af, slot, 1);                                                       \
    LGKM0_FENCE();                                                             \
    MFMA_QUAD(1, 1, af, bfp1);    /* bfp1 dead after */                        \
    if ((t) + 1 < NT) LOAD_BRAW(1, (t) + 1);  /* b1raw(t+1), hides under Q10 */\
    MFMA_QUAD(1, 0, af, bfp0);    /* bfp0 dead after */                        \
    if ((t) + 1 < NT) { VMCNT(16); BARRIER(); }   /* A(t+1) done; b1 stays */  \
} while (0)

__global__ __launch_bounds__(512, 2) void gemm8f_kernel(
    const char* __restrict__ Ab,        // xq [M][K] i8
    const int*  __restrict__ Wq,        // weight_quant [N][K] int32 (raw input)
    const float* __restrict__ sw,       // per-n weight scale
    const float* __restrict__ xs,       // per-m activation scale
    const float* __restrict__ bias,
    float* __restrict__ C) {

    __shared__ __align__(16) char LDSA[2][2][128][128];   // 64 KiB, A only

    const int tid = threadIdx.x;
    const int l   = tid & 63;
    const int w   = tid >> 6;          // wave 0..7
    const int wm  = w >> 2;            // 0..1 (m half)
    const int wn  = w & 3;             // 0..3 (n quarter)
    const int lr  = l & 15;
    const int l4  = l >> 4;            // 0..3
    const int xorv = (lr & 7) << 4;

    // bijective XCD swizzle (256 wg, 32/XCD), m-fastest work order:
    // the 4 m-blocks sharing an n-panel run concurrently on one XCD -> L2 hits
    const int orig = blockIdx.x;
    const int work = (orig & 7) * 32 + (orig >> 3);
    const int gm0 = (work & 3) * 256;
    const int gn0 = (work >> 2) * 256;

    // A staging source geometry (inverse of read-side XOR swizzle), bytes
    const int g_log = (l & 7) ^ ((l >> 3) & 7);
    const int gcol  = g_log * 16;
    const size_t aRow0 = (size_t)(gm0 + w * 8 + (l >> 3));

    // B raw int32 addressing: uniform base + per-lane 32-bit offset (elems)
    const int* bBase = Wq + (size_t)gn0 * Kd;
    const int  bOff0 = (wn * 64 + lr) * Kd + l4 * 16;

    i32x4 af[4][2];                    // A frags (one h-half), 32 VGPR
    i32x4 raw[2][2][4];                // shared raw int32 buffer, 64 VGPR
    i32x4 bfp0[2][2], bfp1[2][2];      // packed i8 B frags, 16+16 VGPR

    i32x4 acc[8][4];
    #pragma unroll
    for (int i = 0; i < 8; ++i)
        #pragma unroll
        for (int j = 0; j < 4; ++j) {
            i32x4 z = {0, 0, 0, 0};
            acc[i][j] = z;
        }

    // prologue: A(0) staged, b1raw(0) issued
    STAGE_AFULL(0, 0);                 // [A:4]
    LOAD_BRAW(1, 0);                   // [A:4, b1:16]
    VMCNT(16);                         // A(0) done; b1 stays in flight
    BARRIER();

    #pragma unroll 1
    for (int tt = 0; tt < NT / 2; ++tt) {
        TILE(0, 1, 2 * tt);
        TILE(1, 0, 2 * tt + 1);
    }

    // epilogue: C = sw[n]*xs[m]*acc + bias[n]
    // C/D layout (dtype-independent): col = lane&15 (n), row = (lane>>4)*4+reg
    #pragma unroll
    for (int bj = 0; bj < 4; ++bj) {
        const int gn = gn0 + wn * 64 + bj * 16 + lr;
        const float sc = sw[gn];
        const float bi = bias[gn];
        #pragma unroll
        for (int ai = 0; ai < 8; ++ai) {
            const int gm = gm0 + wm * 128 + ai * 16 + l4 * 4;
            #pragma unroll
            for (int r = 0; r < 4; ++r)
                C[(size_t)(gm + r) * Nd + gn] =
                    (float)acc[ai][bj][r] * (sc * xs[gm + r]) + bi;
        }
    }
}

// ---------- fallback (ws too small): slow but correct ----------

__global__ __launch_bounds__(256) void naive_kernel(
    const float* __restrict__ x, const int* __restrict__ wq,
    const float* __restrict__ scale, const float* __restrict__ bias,
    float* __restrict__ out) {
    const int n = blockIdx.x * 256 + threadIdx.x;
    const int m = blockIdx.y;
    if (n >= Nd) return;
    const float* xr = x + (size_t)m * Kd;
    const int*   wr = wq + (size_t)n * Kd;
    float s = 0.f;
    for (int k = 0; k < Kd; ++k) s += xr[k] * (float)wr[k];
    out[(size_t)m * Nd + n] = s * scale[n] + bias[n];
}

// ---------- launch ----------

extern "C" void kernel_launch(void* const* d_in, const int* in_sizes, int n_in,
                              void* d_out, int out_size, void* d_ws, size_t ws_size,
                              hipStream_t stream) {
    const float* x     = (const float*)d_in[0];
    const int*   wq    = (const int*)d_in[1];
    const float* scale = (const float*)d_in[2];
    const float* bias  = (const float*)d_in[3];
    float* out = (float*)d_out;

    const size_t x_bytes = (size_t)Md * Kd;              // 4 MiB (i8)
    const size_t s_bytes = (size_t)Md * sizeof(float);   // 4 KiB
    if (ws_size >= x_bytes + s_bytes && d_ws != nullptr) {
        char*  xb = (char*)d_ws;
        float* xs = (float*)(xb + x_bytes);
        convert_x_kernel<<<Md, 256, 0, stream>>>(x, xb, xs);
        gemm8f_kernel<<<256, 512, 0, stream>>>(xb, wq, scale, xs, bias, out);
    } else {
        dim3 grid(Nd / 256, Md);
        naive_kernel<<<grid, 256, 0, stream>>>(x, wq, scale, bias, out);
    }
}

// Round 8
// 295.150 us; speedup vs baseline: 1.6154x; 1.6154x over previous
//
#include <hip/hip_runtime.h>

typedef __attribute__((ext_vector_type(4))) float f32x4;
typedef __attribute__((ext_vector_type(4))) int   i32x4;

static constexpr int Kd = 4096, Nd = 16384, Md = 1024;
static constexpr int BK = 128;          // K-elems (i8) per tile
static constexpr int NT = Kd / BK;      // 32 K-tiles
static constexpr int BM = 128, BN = 256;

// ---------- helpers ----------

__device__ __forceinline__ void gload16(const char* g, char* l) {
    __builtin_amdgcn_global_load_lds(
        (const __attribute__((address_space(1))) void*)g,
        (__attribute__((address_space(3))) void*)l, 16, 0, 0);
}

__device__ __forceinline__ int pack4(int a, int b, int c, int d) {
    return (a & 255) | ((b & 255) << 8) | ((c & 255) << 16) | (d << 24);
}

// ---------- convert X: f32 [M][K] -> per-row absmax-scaled int8 ----------

__global__ __launch_bounds__(256) void convert_x_kernel(
    const float* __restrict__ x, char* __restrict__ xb, float* __restrict__ xs) {
    const int row = blockIdx.x;
    const int t   = threadIdx.x;
    const float* xr = x + (size_t)row * Kd;

    f32x4 v[4];
    float amax = 0.f;
    #pragma unroll
    for (int i = 0; i < 4; ++i) {
        v[i] = *(const f32x4*)(xr + t * 16 + i * 4);
        #pragma unroll
        for (int j = 0; j < 4; ++j) amax = fmaxf(amax, fabsf(v[i][j]));
    }
    #pragma unroll
    for (int off = 32; off; off >>= 1)
        amax = fmaxf(amax, __shfl_xor(amax, off));
    __shared__ float wmax[4];
    if ((t & 63) == 0) wmax[t >> 6] = amax;
    __syncthreads();
    amax = fmaxf(fmaxf(wmax[0], wmax[1]), fmaxf(wmax[2], wmax[3]));
    amax = fmaxf(amax, 1e-20f);

    const float inv = 127.0f / amax;
    i32x4 o;
    #pragma unroll
    for (int i = 0; i < 4; ++i) {
        int q[4];
        #pragma unroll
        for (int j = 0; j < 4; ++j) {
            int qi = __float2int_rn(v[i][j] * inv);
            qi = qi > 127 ? 127 : (qi < -127 ? -127 : qi);
            q[j] = qi;
        }
        o[i] = pack4(q[0], q[1], q[2], q[3]);
    }
    *(i32x4*)(xb + (size_t)row * Kd + t * 16) = o;
    if (t == 0) xs[row] = amax * (1.0f / 127.0f);
}

// ---------- fused 128x256 i8 GEMM, 256 thr / 4 waves / 1 wave-per-SIMD ----------
// C[m,n] = sw[n]*xs[m] * sum_k xq[m,k]*w8[n,k] + bias[n],  w8 = low byte of Wq
// 4 waves = 1M x 4N; per-wave out 128x64; acc 128 regs; VGPR budget 512
// (1 wave/SIMD) -> full fused state fits, NO spill (r7 lesson).
// A: i8 via LDS, 2 slots x 16 KiB, XOR swizzle, gload_lds (4 ops/tile).
// B: raw int32 straight to regs, packed in-reg; j=1 half prefetched a full
// tile ahead (raw1), j=0 half ~0.7 tile ahead (raw0). One barrier per tile.
// Per-tile FIFO (oldest left) + waits, verified incl. prologue/tail:
//  entry: [b1(t):16, b0(t):16] ; VMCNT(16) -> b1 done ; PACK bfp1
//  READ_A lo/hi (16 ds) ; STAGE_A(t+1) (+4) -> [b0:16, A:4]
//  LGKM(8) -> af[0..3] ; H1a(16 MFMA) ; VMCNT(4) -> b0 done ; PACK bfp0
//  LGKM(0) -> af[4..7] ; H1b ; LOAD raw1(t+1) (+16) ; H0a ;
//  LOAD raw0(t+1) (+16) -> [A:4, b1:16, b0:16] ; H0b ;
//  VMCNT(32) -> A(t+1) done ; BARRIER.

#define BARRIER() asm volatile("s_barrier" ::: "memory")
#define SBAR() __builtin_amdgcn_sched_barrier(0)

#define LGKM(n) do {                                                           \
    asm volatile("s_waitcnt lgkmcnt(" #n ")" ::: "memory");                    \
    __builtin_amdgcn_sched_barrier(0);                                         \
} while (0)

#define VMCNT(n) do {                                                          \
    asm volatile("s_waitcnt vmcnt(" #n ")" ::: "memory");                      \
    __builtin_amdgcn_sched_barrier(0);                                         \
} while (0)

// stage full A tile (128 rows x 128 B) for kt into slot: 4 gload_lds/thread
#define STAGE_AFULL(slot, kt) do {                                             \
    _Pragma("unroll")                                                          \
    for (int i_ = 0; i_ < 4; ++i_) {                                           \
        char* lb_ = &LDSA[slot][i_ * 32 + w * 8][0];                           \
        gload16(Ab + (aRow0 + i_ * 32) * (size_t)Kd + (kt) * BK + gcol, lb_);  \
    }                                                                          \
    __builtin_amdgcn_sched_barrier(0);                                         \
} while (0)

// issue 16 dwordx4 raw int32 loads for j-half (j) of tile kt into buf
#define LOAD_BRAW(buf, j, kt) do {                                             \
    _Pragma("unroll")                                                          \
    for (int ni = 0; ni < 2; ++ni)                                             \
        _Pragma("unroll")                                                      \
        for (int kk = 0; kk < 2; ++kk) {                                       \
            const int off_ = bOff0 + ((j) * 32 + ni * 16) * Kd                 \
                             + (kt) * BK + kk * 64;                            \
            _Pragma("unroll")                                                  \
            for (int i = 0; i < 4; ++i)                                        \
                buf[ni][kk][i] = *(const i32x4*)(bBase + off_ + i * 4);        \
        }                                                                      \
    __builtin_amdgcn_sched_barrier(0);                                         \
} while (0)

#define PACK_BF(bfp, buf) do {                                                 \
    _Pragma("unroll")                                                          \
    for (int ni = 0; ni < 2; ++ni)                                             \
        _Pragma("unroll")                                                      \
        for (int kk = 0; kk < 2; ++kk)                                         \
            _Pragma("unroll")                                                  \
            for (int i = 0; i < 4; ++i)                                        \
                bfp[ni][kk][i] = pack4(buf[ni][kk][i][0], buf[ni][kk][i][1],   \
                                       buf[ni][kk][i][2], buf[ni][kk][i][3]);  \
} while (0)

// read A frags for mi in [milo, milo+4) from slot (8 ds_read_b128)
#define READ_A4(slot, milo) do {                                               \
    const char* lA_ = &LDSA[slot][0][0];                                       \
    _Pragma("unroll")                                                          \
    for (int mi = (milo); mi < (milo) + 4; ++mi)                               \
        _Pragma("unroll")                                                      \
        for (int kk = 0; kk < 2; ++kk) {                                       \
            const int row_ = mi * 16 + lr;                                     \
            const int col_ = (l4 * 16 + kk * 64) ^ xorv;                       \
            af[mi][kk] = *(const i32x4*)(lA_ + row_ * 128 + col_);             \
        }                                                                      \
    __builtin_amdgcn_sched_barrier(0);                                         \
} while (0)

// 16 MFMA: mi in [milo,milo+4), acc columns bj0..bj0+1, B frags BF
#define MFMA_HALF(milo, bj0, BF) do {                                          \
    __builtin_amdgcn_s_setprio(1);                                             \
    _Pragma("unroll")                                                          \
    for (int mi = (milo); mi < (milo) + 4; ++mi)                               \
        _Pragma("unroll")                                                      \
        for (int ni = 0; ni < 2; ++ni)                                         \
            _Pragma("unroll")                                                  \
            for (int kk = 0; kk < 2; ++kk)                                     \
                acc[mi][(bj0) + ni] =                                          \
                    __builtin_amdgcn_mfma_i32_16x16x64_i8(                     \
                        af[mi][kk], BF[ni][kk], acc[mi][(bj0) + ni], 0, 0, 0); \
    __builtin_amdgcn_s_setprio(0);                                             \
} while (0)

#define TILE(slot, oslot, t) do {                                              \
    VMCNT(16);                         /* b1raw(t) done; [b0(t):16] */         \
    PACK_BF(bfp1, raw1);                                                       \
    READ_A4(slot, 0);                                                         \
    READ_A4(slot, 4);                                                         \
    if ((t) + 1 < NT) STAGE_AFULL(oslot, (t) + 1);   /* [b0:16, A:4] */        \
    LGKM(8);                           /* af[0..3] ready */                    \
    MFMA_HALF(0, 2, bfp1);             /* H1a */                               \
    if ((t) + 1 < NT) { VMCNT(4); } else { VMCNT(0); }  /* b0raw(t) done */    \
    PACK_BF(bfp0, raw0);                                                       \
    LGKM(0);                           /* af[4..7] ready */                    \
    MFMA_HALF(4, 2, bfp1);             /* H1b; bfp1 dead */                    \
    if ((t) + 1 < NT) LOAD_BRAW(raw1, 1, (t) + 1);   /* [A:4, b1:16] */        \
    MFMA_HALF(0, 0, bfp0);             /* H0a */                               \
    if ((t) + 1 < NT) LOAD_BRAW(raw0, 0, (t) + 1);   /* [A:4,b1:16,b0:16] */   \
    MFMA_HALF(4, 0, bfp0);             /* H0b; bfp0 dead */                    \
    if ((t) + 1 < NT) { VMCNT(32); BARRIER(); }   /* A(t+1) done */            \
} while (0)

__global__ __launch_bounds__(256, 1) void gemm8f_kernel(
    const char* __restrict__ Ab,        // xq [M][K] i8
    const int*  __restrict__ Wq,        // weight_quant [N][K] int32 (raw input)
    const float* __restrict__ sw,       // per-n weight scale
    const float* __restrict__ xs,       // per-m activation scale
    const float* __restrict__ bias,
    float* __restrict__ C) {

    __shared__ __align__(16) char LDSA[2][128][128];   // 32 KiB, A only

    const int tid = threadIdx.x;
    const int l   = tid & 63;
    const int w   = tid >> 6;          // wave 0..3 (n quarter)
    const int lr  = l & 15;
    const int l4  = l >> 4;            // 0..3
    const int xorv = (lr & 7) << 4;

    // bijective XCD swizzle (512 wg, 64/XCD), m-fastest: the 8 m-blocks
    // sharing an n-panel land on one XCD -> B re-reads are L2 hits
    const int orig = blockIdx.x;
    const int work = (orig & 7) * 64 + (orig >> 3);
    const int gm0 = (work & 7) * BM;
    const int gn0 = (work >> 3) * BN;

    // A staging source geometry (inverse of read-side XOR swizzle), bytes
    const int g_log = (l & 7) ^ ((l >> 3) & 7);
    const int gcol  = g_log * 16;
    const size_t aRow0 = (size_t)(gm0 + w * 8 + (l >> 3));

    // B raw int32 addressing: uniform base + per-lane offset (dword units)
    const int* bBase = Wq + (size_t)gn0 * Kd;
    const int  bOff0 = (w * 64 + lr) * Kd + l4 * 16;

    i32x4 af[8][2];                    // A frags, 64 regs
    i32x4 raw1[2][2][4], raw0[2][2][4];// raw int32 prefetch, 64+64 regs
    i32x4 bfp1[2][2], bfp0[2][2];      // packed i8 B frags, 16+16 regs

    i32x4 acc[8][4];                   // 128 regs
    #pragma unroll
    for (int i = 0; i < 8; ++i)
        #pragma unroll
        for (int j = 0; j < 4; ++j) {
            i32x4 z = {0, 0, 0, 0};
            acc[i][j] = z;
        }

    // prologue: A(0) staged, b1raw(0)+b0raw(0) issued
    STAGE_AFULL(0, 0);                 // [A:4]
    LOAD_BRAW(raw1, 1, 0);             // [A:4, b1:16]
    LOAD_BRAW(raw0, 0, 0);             // [A:4, b1:16, b0:16]
    VMCNT(32);                         // A(0) done
    BARRIER();

    #pragma unroll 1
    for (int tt = 0; tt < NT / 2; ++tt) {
        TILE(0, 1, 2 * tt);
        TILE(1, 0, 2 * tt + 1);
    }

    // epilogue: C = sw[n]*xs[m]*acc + bias[n]
    // C/D layout (dtype-independent): col = lane&15 (n), row = (lane>>4)*4+reg
    #pragma unroll
    for (int bj = 0; bj < 4; ++bj) {
        const int gn = gn0 + w * 64 + bj * 16 + lr;
        const float sc = sw[gn];
        const float bi = bias[gn];
        #pragma unroll
        for (int ai = 0; ai < 8; ++ai) {
            const int gm = gm0 + ai * 16 + l4 * 4;
            #pragma unroll
            for (int r = 0; r < 4; ++r)
                C[(size_t)(gm + r) * Nd + gn] =
                    (float)acc[ai][bj][r] * (sc * xs[gm + r]) + bi;
        }
    }
}

// ---------- fallback (ws too small): slow but correct ----------

__global__ __launch_bounds__(256) void naive_kernel(
    const float* __restrict__ x, const int* __restrict__ wq,
    const float* __restrict__ scale, const float* __restrict__ bias,
    float* __restrict__ out) {
    const int n = blockIdx.x * 256 + threadIdx.x;
    const int m = blockIdx.y;
    if (n >= Nd) return;
    const float* xr = x + (size_t)m * Kd;
    const int*   wr = wq + (size_t)n * Kd;
    float s = 0.f;
    for (int k = 0; k < Kd; ++k) s += xr[k] * (float)wr[k];
    out[(size_t)m * Nd + n] = s * scale[n] + bias[n];
}

// ---------- launch ----------

extern "C" void kernel_launch(void* const* d_in, const int* in_sizes, int n_in,
                              void* d_out, int out_size, void* d_ws, size_t ws_size,
                              hipStream_t stream) {
    const float* x     = (const float*)d_in[0];
    const int*   wq    = (const int*)d_in[1];
    const float* scale = (const float*)d_in[2];
    const float* bias  = (const float*)d_in[3];
    float* out = (float*)d_out;

    const size_t x_bytes = (size_t)Md * Kd;              // 4 MiB (i8)
    const size_t s_bytes = (size_t)Md * sizeof(float);   // 4 KiB
    if (ws_size >= x_bytes + s_bytes && d_ws != nullptr) {
        char*  xb = (char*)d_ws;
        float* xs = (float*)(xb + x_bytes);
        convert_x_kernel<<<Md, 256, 0, stream>>>(x, xb, xs);
        const int nwg = (Md / BM) * (Nd / BN);           // 512
        gemm8f_kernel<<<nwg, 256, 0, stream>>>(xb, wq, scale, xs, bias, out);
    } else {
        dim3 grid(Nd / 256, Md);
        naive_kernel<<<grid, 256, 0, stream>>>(x, wq, scale, bias, out);
    }
}